// Round 20
// baseline (275.592 us; speedup 1.0000x reference)
//
#include <hip/hip_runtime.h>

#define NN 100000
#define NE 800000
#define NG 128
#define U  128
#define NGIN 3
#define NBUCK 64
#define NPB 1563                 // ceil(NN / NBUCK)
#define BCAP 14336               // fixed bucket capacity (mean 12500, sigma ~111)
#define ACHUNK 4096
#define NAB ((NE + ACHUNK - 1) / ACHUNK)   // 196 phase-A blocks
#define ZP 136                   // tile pitch in bf16 (272B: 16B-aligned)
#define CVTB (NN * U / 4 / 256)  // 12500 convert blocks (exact)

typedef short bf16x8 __attribute__((ext_vector_type(8)));
typedef float f32x4 __attribute__((ext_vector_type(4)));
typedef float f32x2 __attribute__((ext_vector_type(2)));

__device__ __forceinline__ unsigned short f2b(float f) {
    union { float f; unsigned u; } v; v.f = f;
    unsigned r = v.u + 0x7FFF + ((v.u >> 16) & 1);   // RNE
    return (unsigned short)(r >> 16);
}
__device__ __forceinline__ float blo(unsigned u) {
    union { unsigned u; float f; } v; v.u = u << 16; return v.f;
}
__device__ __forceinline__ float bhi(unsigned u) {
    union { unsigned u; float f; } v; v.u = u & 0xffff0000u; return v.f;
}
__device__ __forceinline__ unsigned cvtpk(float lo, float hi) {
    unsigned r;
    asm("v_cvt_pk_bf16_f32 %0, %1, %2" : "=v"(r) : "v"(lo), "v"(hi));
    return r;
}
// fp8 e4m3 (HW native, RNE, self-consistent encode/decode)
__device__ __forceinline__ f32x2 fp8x2_f32(unsigned v) {
    return __builtin_amdgcn_cvt_pk_f32_fp8((int)v, false);
}
__device__ __forceinline__ unsigned f32x2_fp8(float a, float b) {
    return (unsigned)__builtin_amdgcn_cvt_pk_fp8_f32(a, b, 0, false);
}

// ---------------------------------------------------------------------------
// merged prep: convert x->bf16+fp8 | pack W frags | bn scale/shift |
// zero pooled | init bucket cursors
// ---------------------------------------------------------------------------
__global__ __launch_bounds__(256) void prep_k(const float* __restrict__ x,
                                              unsigned short* __restrict__ hb,
                                              unsigned* __restrict__ hb8,
                                              const float* __restrict__ W1,
                                              const float* __restrict__ W2,
                                              unsigned short* __restrict__ wfrag,
                                              const float* __restrict__ b2,
                                              const float* __restrict__ gam,
                                              const float* __restrict__ bet,
                                              const float* __restrict__ bmn,
                                              const float* __restrict__ bvr,
                                              float* __restrict__ sclp,
                                              float* __restrict__ shp,
                                              float* __restrict__ pooled,
                                              int* __restrict__ bcur) {
    const int b = blockIdx.x;
    const int tid = threadIdx.x;
    if (b < CVTB) {
        int i = b * 256 + tid;
        float4 v = reinterpret_cast<const float4*>(x)[i];
        uint2 o;
        o.x = (unsigned)f2b(v.x) | ((unsigned)f2b(v.y) << 16);
        o.y = (unsigned)f2b(v.z) | ((unsigned)f2b(v.w) << 16);
        reinterpret_cast<uint2*>(hb)[i] = o;
        unsigned p = f32x2_fp8(v.x, v.y) | (f32x2_fp8(v.z, v.w) << 16);
        hb8[i] = p;
    } else if (b < CVTB + 6) {
        int bb = b - CVTB;
        const float* src = ((bb & 1) ? W2 : W1) + (size_t)(bb >> 1) * U * U;
        unsigned short* dst = wfrag + (size_t)bb * 16384;
        for (int e = tid; e < 16384; e += 256) {
            int j = e & 7, lane = (e >> 3) & 63, ks = (e >> 9) & 3, ct = e >> 11;
            int k = ks * 32 + ((lane >> 4) << 3) + j;
            int c = ct * 16 + (lane & 15);
            dst[e] = f2b(src[k * U + c]);
        }
    } else if (b < CVTB + 6 + 3) {
        if (tid < 128) {
            int i = (b - CVTB - 6) * 128 + tid;
            float s = gam[i] * rsqrtf(bvr[i] + 1e-3f);
            sclp[i] = s;
            shp[i] = (b2[i] - bmn[i]) * s + bet[i];
        }
    } else if (b < CVTB + 6 + 3 + 24) {
        int bb = b - CVTB - 6 - 3;
        int i0 = bb * 2048 + tid;
#pragma unroll
        for (int j = 0; j < 8; ++j) pooled[i0 + j * 256] = 0.f;
    } else {
        if (tid < NBUCK) bcur[tid] = tid * BCAP;
    }
}

// ---------------------------------------------------------------------------
// CSR build: phaseA (fixed-capacity bucket scatter) -> phaseB (per-node sort)
// ---------------------------------------------------------------------------
__global__ __launch_bounds__(256) void phaseA_k(const int* __restrict__ ei,
                                                const float* __restrict__ ew,
                                                int* __restrict__ bcur,
                                                uint2* __restrict__ tmp) {
    __shared__ int lh[NBUCK];
    int tid = threadIdx.x;
    if (tid < NBUCK) lh[tid] = 0;
    __syncthreads();
    int e0 = blockIdx.x * ACHUNK;
    int eend = min(e0 + ACHUNK, NE);
    for (int e = e0 + tid; e < eend; e += 256)
        atomicAdd(&lh[ei[e] / NPB], 1);
    __syncthreads();
    if (tid < NBUCK) {
        int c = lh[tid];
        lh[tid] = c ? atomicAdd(&bcur[tid], c) : 0;
    }
    __syncthreads();
    for (int e = e0 + tid; e < eend; e += 256) {
        int d = ei[e];
        int pos = atomicAdd(&lh[d / NPB], 1);
        uint2 r;
        r.x = ((unsigned)ei[NE + e] << 15) | (unsigned)f2b(ew[e]);
        r.y = (unsigned)d;
        tmp[pos] = r;
    }
}

__global__ __launch_bounds__(256) void phaseB_k(const uint2* __restrict__ tmp,
                                                const int* __restrict__ bcur,
                                                int* __restrict__ rowptr,
                                                int* __restrict__ rowend,
                                                unsigned* __restrict__ esw) {
    __shared__ int cnt[1792];
    __shared__ int cend[1792];
    __shared__ int ws[4];
    const int tid = threadIdx.x;
    const int b = blockIdx.x;
    const int n0 = b * NPB;
    const int npb = min(NPB, NN - n0);
    const int wbeg = b * BCAP;
    const int wend = bcur[b];

    for (int i = tid; i < 1792; i += 256) cnt[i] = 0;
    __syncthreads();
    for (int e = wbeg + tid; e < wend; e += 256)
        atomicAdd(&cnt[(int)tmp[e].y - n0], 1);
    __syncthreads();
    int base = tid * 7;
    int v[7]; int s = 0;
#pragma unroll
    for (int k = 0; k < 7; ++k) { v[k] = cnt[base + k]; s += v[k]; }
    int lane = tid & 63, wid = tid >> 6;
    int incl = s;
#pragma unroll
    for (int off = 1; off < 64; off <<= 1) {
        int n = __shfl_up(incl, off);
        if (lane >= off) incl += n;
    }
    if (lane == 63) ws[wid] = incl;
    __syncthreads();
    if (tid == 0) {
        int a = 0;
#pragma unroll
        for (int w = 0; w < 4; ++w) { int t = ws[w]; ws[w] = a; a += t; }
    }
    __syncthreads();
    int run = wbeg + ws[wid] + (incl - s);
#pragma unroll
    for (int k = 0; k < 7; ++k) {
        cnt[base + k] = run;
        cend[base + k] = run + v[k];
        run += v[k];
    }
    __syncthreads();
    for (int i = tid; i < npb; i += 256) {
        rowptr[n0 + i] = cnt[i];
        rowend[n0 + i] = cend[i];
    }
    __syncthreads();
    for (int e = wbeg + tid; e < wend; e += 256) {
        uint2 r = tmp[e];
        int pos = atomicAdd(&cnt[(int)r.y - n0], 1);
        esw[pos] = r.x;
    }
}

// ---------------------------------------------------------------------------
// fused gather + 2x matmul per layer (R13 structure).
// Neighbor rows read from the fp8 table (128B rows — half the granules);
// self term + dense path stay bf16/f32 exact.
// ---------------------------------------------------------------------------
template <bool STORE_H>
__global__ __launch_bounds__(256) void fusedgd_k(const unsigned short* __restrict__ hin,
                                                 const unsigned short* __restrict__ hin8,
                                                 const unsigned* __restrict__ esw,
                                                 const int* __restrict__ rowptr,
                                                 const int* __restrict__ rowend,
                                                 const unsigned short* __restrict__ wf1,
                                                 const unsigned short* __restrict__ wf2,
                                                 const float* __restrict__ bias1,
                                                 const float* __restrict__ sclp,
                                                 const float* __restrict__ shp,
                                                 const int* __restrict__ gidx,
                                                 unsigned short* __restrict__ hout,
                                                 unsigned char* __restrict__ hout8,
                                                 float* __restrict__ pooled,
                                                 int pool_off) {
    __shared__ unsigned short zt[16 * ZP];
    __shared__ unsigned short z1t[16 * ZP];
    const int tid = threadIdx.x;
    const int lane = tid & 63;
    const int wid = tid >> 6;
    const int r0 = blockIdx.x * 16;           // NN % 16 == 0
    const unsigned* hp = reinterpret_cast<const unsigned*>(hin);
    unsigned* ztd = reinterpret_cast<unsigned*>(zt);

    // ---- phase 1: gather 4 rows per wave (neighbors from fp8 rows) ----
    for (int q = 0; q < 4; ++q) {
        int row = wid * 4 + q;
        int node = r0 + row;
        int beg = rowptr[node], end = rowend[node];
        float ax[8], ay[8];
#pragma unroll
        for (int k = 0; k < 8; ++k) { ax[k] = 0.f; ay[k] = 0.f; }
        for (int cb = beg; cb < end; cb += 64) {
            int n = min(end - cb, 64);
            unsigned rec = (lane < n) ? esw[cb + lane] : 0u;   // pad: src 0, w 0
            int sv = (int)(rec >> 15);
            float wv = __uint_as_float((rec & 0x7FFFu) << 16);
            for (int i = 0; i < n; i += 8) {
                int s_[8]; float w_[8]; unsigned h_[8];
#pragma unroll
                for (int k = 0; k < 8; ++k) {
                    s_[k] = __shfl(sv, i + k);
                    w_[k] = __shfl(wv, i + k);
                }
#pragma unroll
                for (int k = 0; k < 8; ++k)
                    h_[k] = hin8[(size_t)s_[k] * 64 + lane];   // 2 fp8 (cols 2l,2l+1)
#pragma unroll
                for (int k = 0; k < 8; ++k) {
                    f32x2 f = fp8x2_f32(h_[k]);
                    ax[k] = fmaf(f.x, w_[k], ax[k]);
                    ay[k] = fmaf(f.y, w_[k], ay[k]);
                }
            }
        }
        float axs = ((ax[0] + ax[1]) + (ax[2] + ax[3])) + ((ax[4] + ax[5]) + (ax[6] + ax[7]));
        float ays = ((ay[0] + ay[1]) + (ay[2] + ay[3])) + ((ay[4] + ay[5]) + (ay[6] + ay[7]));
        unsigned hn = hp[(size_t)node * 64 + lane];            // self: exact bf16
        axs = fmaf(1.5f, blo(hn), axs);
        ays = fmaf(1.5f, bhi(hn), ays);
        ztd[row * (ZP / 2) + lane] = cvtpk(axs, ays);
    }
    __syncthreads();

    // ---- phase 2: m1, wave handles ct in {2wid, 2wid+1} ----
    const int c = lane & 15;
    const int g = lane >> 4;
    bf16x8 a1[4];
#pragma unroll
    for (int ks = 0; ks < 4; ++ks)
        a1[ks] = *reinterpret_cast<const bf16x8*>(zt + c * ZP + ks * 32 + g * 8);

    f32x4 acc1[2];
    acc1[0] = (f32x4){0.f, 0.f, 0.f, 0.f};
    acc1[1] = (f32x4){0.f, 0.f, 0.f, 0.f};
#pragma unroll
    for (int t = 0; t < 2; ++t) {
        int ct = wid * 2 + t;
#pragma unroll
        for (int ks = 0; ks < 4; ++ks) {
            bf16x8 b = *reinterpret_cast<const bf16x8*>(
                wf1 + (((ct * 4 + ks) * 64 + lane) << 3));
            acc1[t] = __builtin_amdgcn_mfma_f32_16x16x32_bf16(a1[ks], b, acc1[t], 0, 0, 0);
        }
    }
#pragma unroll
    for (int t = 0; t < 2; ++t) {
        int col = (wid * 2 + t) * 16 + c;
        float bv = bias1[col];
#pragma unroll
        for (int j = 0; j < 4; ++j) {
            int row = g * 4 + j;
            z1t[row * ZP + col] = f2b(fmaxf(acc1[t][j] + bv, 0.f));
        }
    }
    __syncthreads();

    // ---- phase 3: m2 ----
    bf16x8 a2[4];
#pragma unroll
    for (int ks = 0; ks < 4; ++ks)
        a2[ks] = *reinterpret_cast<const bf16x8*>(z1t + c * ZP + ks * 32 + g * 8);

    f32x4 acc2[2];
    acc2[0] = (f32x4){0.f, 0.f, 0.f, 0.f};
    acc2[1] = (f32x4){0.f, 0.f, 0.f, 0.f};
#pragma unroll
    for (int t = 0; t < 2; ++t) {
        int ct = wid * 2 + t;
#pragma unroll
        for (int ks = 0; ks < 4; ++ks) {
            bf16x8 b = *reinterpret_cast<const bf16x8*>(
                wf2 + (((ct * 4 + ks) * 64 + lane) << 3));
            acc2[t] = __builtin_amdgcn_mfma_f32_16x16x32_bf16(a2[ks], b, acc2[t], 0, 0, 0);
        }
    }

    // ep2: bn + relu -> hout (bf16 + fp8), pooled (f32, pre-quantization)
    int ga = gidx[r0], gb = gidx[r0 + 15];
    bool uni = (ga == gb);
#pragma unroll
    for (int t = 0; t < 2; ++t) {
        int col = (wid * 2 + t) * 16 + c;
        float scl = sclp[col], sh = shp[col];
        float hv[4];
        float psum = 0.f;
#pragma unroll
        for (int j = 0; j < 4; ++j) {
            int row = g * 4 + j;
            float v = fmaxf(fmaf(acc2[t][j], scl, sh), 0.f);
            hv[j] = v;
            psum += v;
            if (STORE_H) hout[(size_t)(r0 + row) * U + col] = f2b(v);
        }
        if (STORE_H) {
            unsigned pA = f32x2_fp8(hv[0], hv[1]);
            unsigned pB = f32x2_fp8(hv[2], hv[3]);
            int rb = r0 + g * 4;
            hout8[(size_t)(rb + 0) * U + col] = (unsigned char)(pA & 0xFF);
            hout8[(size_t)(rb + 1) * U + col] = (unsigned char)((pA >> 8) & 0xFF);
            hout8[(size_t)(rb + 2) * U + col] = (unsigned char)(pB & 0xFF);
            hout8[(size_t)(rb + 3) * U + col] = (unsigned char)((pB >> 8) & 0xFF);
        }
        if (uni) {
            psum += __shfl_xor(psum, 16);
            psum += __shfl_xor(psum, 32);
            if (lane < 16)
                unsafeAtomicAdd(&pooled[(size_t)ga * (NGIN * U) + pool_off + col], psum);
        } else {
#pragma unroll
            for (int j = 0; j < 4; ++j)
                unsafeAtomicAdd(&pooled[(size_t)gidx[r0 + g * 4 + j] * (NGIN * U) + pool_off + col], hv[j]);
        }
    }
}

// ---------------------------------------------------------------------------
// merged readout MLP
// ---------------------------------------------------------------------------
__global__ __launch_bounds__(128) void mlp_k(const float* __restrict__ pooled,
                                             const float* __restrict__ Wm1,
                                             const float* __restrict__ bm1,
                                             const float* __restrict__ Wm2,
                                             const float* __restrict__ bm2,
                                             float* __restrict__ out) {
    __shared__ float sp[NGIN * U];
    __shared__ float sg[128];
    int gi = blockIdx.x, c = threadIdx.x;
    for (int j = c; j < NGIN * U; j += 128) sp[j] = pooled[(size_t)gi * (NGIN * U) + j];
    __syncthreads();
    float acc = bm1[c];
    for (int k = 0; k < NGIN * U; ++k) acc = fmaf(sp[k], Wm1[(size_t)k * 128 + c], acc);
    sg[c] = fmaxf(acc, 0.f);
    __syncthreads();
    if (c < 16) {
        float a2 = bm2[c];
        for (int k = 0; k < 128; ++k) a2 = fmaf(sg[k], Wm2[k * 16 + c], a2);
        out[gi * 16 + c] = a2;
    }
}

extern "C" void kernel_launch(void* const* d_in, const int* in_sizes, int n_in,
                              void* d_out, int out_size, void* d_ws, size_t ws_size,
                              hipStream_t stream) {
    const float* x   = (const float*)d_in[0];
    const int*   ei  = (const int*)d_in[1];
    const float* ew  = (const float*)d_in[2];
    const int*   gix = (const int*)d_in[3];
    const float* W1  = (const float*)d_in[4];
    const float* b1  = (const float*)d_in[5];
    const float* W2  = (const float*)d_in[6];
    const float* b2  = (const float*)d_in[7];
    const float* gam = (const float*)d_in[8];
    const float* bet = (const float*)d_in[9];
    const float* bmn = (const float*)d_in[10];
    const float* bvr = (const float*)d_in[11];
    const float* Wm1 = (const float*)d_in[12];
    const float* bm1 = (const float*)d_in[13];
    const float* Wm2 = (const float*)d_in[14];
    const float* bm2 = (const float*)d_in[15];
    float* out = (float*)d_out;

    unsigned short* hb0 = (unsigned short*)d_ws;            // bf16 [NN*U]
    unsigned short* hb1 = hb0 + (size_t)NN * U;
    unsigned char* h8a = (unsigned char*)(hb1 + (size_t)NN * U);  // fp8 [NN*U]
    unsigned char* h8b = h8a + (size_t)NN * U;
    float* pooled = (float*)(h8b + (size_t)NN * U);
    unsigned short* wfrag = (unsigned short*)(pooled + (size_t)NG * (NGIN * U));
    unsigned* esw = (unsigned*)(wfrag + 6 * 16384);
    uint2* tmp    = (uint2*)(esw + (size_t)NBUCK * BCAP);
    int*   rowptr = (int*)(tmp + (size_t)NBUCK * BCAP);
    int*   rowend = rowptr + NN;
    int*   bcur   = rowend + NN;
    float* sclp   = (float*)(bcur + NBUCK);
    float* shp    = sclp + NGIN * U;

    prep_k<<<CVTB + 6 + 3 + 24 + 1, 256, 0, stream>>>(
        x, hb0, (unsigned*)h8a, W1, W2, wfrag, b2, gam, bet, bmn, bvr,
        sclp, shp, pooled, bcur);
    phaseA_k<<<NAB, 256, 0, stream>>>(ei, ew, bcur, tmp);
    phaseB_k<<<NBUCK, 256, 0, stream>>>(tmp, bcur, rowptr, rowend, esw);

    // L1: x -> h1 ; L2: h1 -> h2 ; L3: h2 -> pooled only
    fusedgd_k<true><<<NN / 16, 256, 0, stream>>>(
        hb0, (const unsigned short*)h8a, esw, rowptr, rowend,
        wfrag, wfrag + 16384,
        b1, sclp, shp, gix, hb1, h8b, pooled, 0);
    fusedgd_k<true><<<NN / 16, 256, 0, stream>>>(
        hb1, (const unsigned short*)h8b, esw, rowptr, rowend,
        wfrag + 2 * 16384, wfrag + 3 * 16384,
        b1 + U, sclp + U, shp + U, gix, hb0, h8a, pooled, U);
    fusedgd_k<false><<<NN / 16, 256, 0, stream>>>(
        hb0, (const unsigned short*)h8a, esw, rowptr, rowend,
        wfrag + 4 * 16384, wfrag + 5 * 16384,
        b1 + 2 * U, sclp + 2 * U, shp + 2 * U, gix, hb1, h8b, pooled, 2 * U);

    mlp_k<<<NG, 128, 0, stream>>>(pooled, Wm1, bm1, Wm2, bm2, out);
}

// Round 21
// 262.799 us; speedup vs baseline: 1.0487x; 1.0487x over previous
//
#include <hip/hip_runtime.h>

#define NN 100000
#define NE 800000
#define NG 128
#define U  128
#define NGIN 3
#define NBUCK 64
#define NPB 1563                 // ceil(NN / NBUCK)
#define BCAP 14336               // fixed bucket capacity (mean 12500, sigma ~111)
#define ACHUNK 4096
#define NAB ((NE + ACHUNK - 1) / ACHUNK)   // 196 phase-A blocks
#define ZP 136                   // tile pitch in bf16 (272B: 16B-aligned)
#define CVTB (NN * U / 4 / 256)  // 12500 convert blocks (exact)

typedef short bf16x8 __attribute__((ext_vector_type(8)));
typedef float f32x4 __attribute__((ext_vector_type(4)));

__device__ __forceinline__ unsigned short f2b(float f) {
    union { float f; unsigned u; } v; v.f = f;
    unsigned r = v.u + 0x7FFF + ((v.u >> 16) & 1);   // RNE
    return (unsigned short)(r >> 16);
}
__device__ __forceinline__ float blo(unsigned u) {
    union { unsigned u; float f; } v; v.u = u << 16; return v.f;
}
__device__ __forceinline__ float bhi(unsigned u) {
    union { unsigned u; float f; } v; v.u = u & 0xffff0000u; return v.f;
}
__device__ __forceinline__ unsigned cvtpk(float lo, float hi) {
    unsigned r;
    asm("v_cvt_pk_bf16_f32 %0, %1, %2" : "=v"(r) : "v"(lo), "v"(hi));
    return r;
}

// ---------------------------------------------------------------------------
// merged prep: convert x->bf16 | pack W frags | bn scale/shift |
// zero pooled | init bucket cursors (b*BCAP)
// ---------------------------------------------------------------------------
__global__ __launch_bounds__(256) void prep_k(const float* __restrict__ x,
                                              unsigned short* __restrict__ hb,
                                              const float* __restrict__ W1,
                                              const float* __restrict__ W2,
                                              unsigned short* __restrict__ wfrag,
                                              const float* __restrict__ b2,
                                              const float* __restrict__ gam,
                                              const float* __restrict__ bet,
                                              const float* __restrict__ bmn,
                                              const float* __restrict__ bvr,
                                              float* __restrict__ sclp,
                                              float* __restrict__ shp,
                                              float* __restrict__ pooled,
                                              int* __restrict__ bcur) {
    const int b = blockIdx.x;
    const int tid = threadIdx.x;
    if (b < CVTB) {
        int i = b * 256 + tid;
        float4 v = reinterpret_cast<const float4*>(x)[i];
        uint2 o;
        o.x = (unsigned)f2b(v.x) | ((unsigned)f2b(v.y) << 16);
        o.y = (unsigned)f2b(v.z) | ((unsigned)f2b(v.w) << 16);
        reinterpret_cast<uint2*>(hb)[i] = o;
    } else if (b < CVTB + 6) {
        int bb = b - CVTB;
        const float* src = ((bb & 1) ? W2 : W1) + (size_t)(bb >> 1) * U * U;
        unsigned short* dst = wfrag + (size_t)bb * 16384;
        for (int e = tid; e < 16384; e += 256) {
            int j = e & 7, lane = (e >> 3) & 63, ks = (e >> 9) & 3, ct = e >> 11;
            int k = ks * 32 + ((lane >> 4) << 3) + j;
            int c = ct * 16 + (lane & 15);
            dst[e] = f2b(src[k * U + c]);
        }
    } else if (b < CVTB + 6 + 3) {
        if (tid < 128) {
            int i = (b - CVTB - 6) * 128 + tid;
            float s = gam[i] * rsqrtf(bvr[i] + 1e-3f);
            sclp[i] = s;
            shp[i] = (b2[i] - bmn[i]) * s + bet[i];
        }
    } else if (b < CVTB + 6 + 3 + 24) {
        int bb = b - CVTB - 6 - 3;
        int i0 = bb * 2048 + tid;
#pragma unroll
        for (int j = 0; j < 8; ++j) pooled[i0 + j * 256] = 0.f;
    } else {
        if (tid < NBUCK) bcur[tid] = tid * BCAP;
    }
}

// ---------------------------------------------------------------------------
// CSR build: phaseA (fixed-capacity bucket scatter) -> phaseB (per-node sort)
// ---------------------------------------------------------------------------
__global__ __launch_bounds__(256) void phaseA_k(const int* __restrict__ ei,
                                                const float* __restrict__ ew,
                                                int* __restrict__ bcur,
                                                uint2* __restrict__ tmp) {
    __shared__ int lh[NBUCK];
    int tid = threadIdx.x;
    if (tid < NBUCK) lh[tid] = 0;
    __syncthreads();
    int e0 = blockIdx.x * ACHUNK;
    int eend = min(e0 + ACHUNK, NE);
    for (int e = e0 + tid; e < eend; e += 256)
        atomicAdd(&lh[ei[e] / NPB], 1);
    __syncthreads();
    if (tid < NBUCK) {
        int c = lh[tid];
        lh[tid] = c ? atomicAdd(&bcur[tid], c) : 0;
    }
    __syncthreads();
    for (int e = e0 + tid; e < eend; e += 256) {
        int d = ei[e];
        int pos = atomicAdd(&lh[d / NPB], 1);
        uint2 r;
        r.x = ((unsigned)ei[NE + e] << 15) | (unsigned)f2b(ew[e]);
        r.y = (unsigned)d;
        tmp[pos] = r;
    }
}

__global__ __launch_bounds__(256) void phaseB_k(const uint2* __restrict__ tmp,
                                                const int* __restrict__ bcur,
                                                int* __restrict__ rowptr,
                                                int* __restrict__ rowend,
                                                unsigned* __restrict__ esw) {
    __shared__ int cnt[1792];
    __shared__ int cend[1792];
    __shared__ int ws[4];
    const int tid = threadIdx.x;
    const int b = blockIdx.x;
    const int n0 = b * NPB;
    const int npb = min(NPB, NN - n0);
    const int wbeg = b * BCAP;
    const int wend = bcur[b];           // wbeg + actual count (phaseA done)

    for (int i = tid; i < 1792; i += 256) cnt[i] = 0;
    __syncthreads();
    for (int e = wbeg + tid; e < wend; e += 256)
        atomicAdd(&cnt[(int)tmp[e].y - n0], 1);
    __syncthreads();
    int base = tid * 7;
    int v[7]; int s = 0;
#pragma unroll
    for (int k = 0; k < 7; ++k) { v[k] = cnt[base + k]; s += v[k]; }
    int lane = tid & 63, wid = tid >> 6;
    int incl = s;
#pragma unroll
    for (int off = 1; off < 64; off <<= 1) {
        int n = __shfl_up(incl, off);
        if (lane >= off) incl += n;
    }
    if (lane == 63) ws[wid] = incl;
    __syncthreads();
    if (tid == 0) {
        int a = 0;
#pragma unroll
        for (int w = 0; w < 4; ++w) { int t = ws[w]; ws[w] = a; a += t; }
    }
    __syncthreads();
    int run = wbeg + ws[wid] + (incl - s);
#pragma unroll
    for (int k = 0; k < 7; ++k) {
        cnt[base + k] = run;
        cend[base + k] = run + v[k];
        run += v[k];
    }
    __syncthreads();
    for (int i = tid; i < npb; i += 256) {
        rowptr[n0 + i] = cnt[i];
        rowend[n0 + i] = cend[i];
    }
    __syncthreads();
    for (int e = wbeg + tid; e < wend; e += 256) {
        uint2 r = tmp[e];
        int pos = atomicAdd(&cnt[(int)r.y - n0], 1);
        esw[pos] = r.x;
    }
}

// ---------------------------------------------------------------------------
// fused gather + 2x matmul per layer (R13 structure — measured best).
// Block = one 16-node strip, 4 waves. STORE_H=false for the last layer.
// ---------------------------------------------------------------------------
template <bool STORE_H>
__global__ __launch_bounds__(256) void fusedgd_k(const unsigned short* __restrict__ hin,
                                                 const unsigned* __restrict__ esw,
                                                 const int* __restrict__ rowptr,
                                                 const int* __restrict__ rowend,
                                                 const unsigned short* __restrict__ wf1,
                                                 const unsigned short* __restrict__ wf2,
                                                 const float* __restrict__ bias1,
                                                 const float* __restrict__ sclp,
                                                 const float* __restrict__ shp,
                                                 const int* __restrict__ gidx,
                                                 unsigned short* __restrict__ hout,
                                                 float* __restrict__ pooled,
                                                 int pool_off) {
    __shared__ unsigned short zt[16 * ZP];
    __shared__ unsigned short z1t[16 * ZP];
    const int tid = threadIdx.x;
    const int lane = tid & 63;
    const int wid = tid >> 6;
    const int r0 = blockIdx.x * 16;           // NN % 16 == 0
    const unsigned* hp = reinterpret_cast<const unsigned*>(hin);
    unsigned* ztd = reinterpret_cast<unsigned*>(zt);

    // ---- phase 1: gather 4 rows per wave ----
    for (int q = 0; q < 4; ++q) {
        int row = wid * 4 + q;
        int node = r0 + row;
        int beg = rowptr[node], end = rowend[node];
        float ax[8], ay[8];
#pragma unroll
        for (int k = 0; k < 8; ++k) { ax[k] = 0.f; ay[k] = 0.f; }
        for (int cb = beg; cb < end; cb += 64) {
            int n = min(end - cb, 64);
            unsigned rec = (lane < n) ? esw[cb + lane] : 0u;   // pad: src 0, w 0
            int sv = (int)(rec >> 15);
            float wv = __uint_as_float((rec & 0x7FFFu) << 16);
            for (int i = 0; i < n; i += 8) {
                int s_[8]; float w_[8]; unsigned h_[8];
#pragma unroll
                for (int k = 0; k < 8; ++k) {
                    s_[k] = __shfl(sv, i + k);
                    w_[k] = __shfl(wv, i + k);
                }
#pragma unroll
                for (int k = 0; k < 8; ++k)
                    h_[k] = hp[(size_t)s_[k] * 64 + lane];
#pragma unroll
                for (int k = 0; k < 8; ++k) {
                    ax[k] = fmaf(blo(h_[k]), w_[k], ax[k]);
                    ay[k] = fmaf(bhi(h_[k]), w_[k], ay[k]);
                }
            }
        }
        float axs = ((ax[0] + ax[1]) + (ax[2] + ax[3])) + ((ax[4] + ax[5]) + (ax[6] + ax[7]));
        float ays = ((ay[0] + ay[1]) + (ay[2] + ay[3])) + ((ay[4] + ay[5]) + (ay[6] + ay[7]));
        unsigned hn = hp[(size_t)node * 64 + lane];
        axs = fmaf(1.5f, blo(hn), axs);
        ays = fmaf(1.5f, bhi(hn), ays);
        ztd[row * (ZP / 2) + lane] = cvtpk(axs, ays);   // cols 2*lane, 2*lane+1
    }
    __syncthreads();

    // ---- phase 2: m1, wave handles ct in {2wid, 2wid+1} ----
    const int c = lane & 15;
    const int g = lane >> 4;
    bf16x8 a1[4];
#pragma unroll
    for (int ks = 0; ks < 4; ++ks)
        a1[ks] = *reinterpret_cast<const bf16x8*>(zt + c * ZP + ks * 32 + g * 8);

    f32x4 acc1[2];
    acc1[0] = (f32x4){0.f, 0.f, 0.f, 0.f};
    acc1[1] = (f32x4){0.f, 0.f, 0.f, 0.f};
#pragma unroll
    for (int t = 0; t < 2; ++t) {
        int ct = wid * 2 + t;
#pragma unroll
        for (int ks = 0; ks < 4; ++ks) {
            bf16x8 b = *reinterpret_cast<const bf16x8*>(
                wf1 + (((ct * 4 + ks) * 64 + lane) << 3));
            acc1[t] = __builtin_amdgcn_mfma_f32_16x16x32_bf16(a1[ks], b, acc1[t], 0, 0, 0);
        }
    }
#pragma unroll
    for (int t = 0; t < 2; ++t) {
        int col = (wid * 2 + t) * 16 + c;
        float bv = bias1[col];
#pragma unroll
        for (int j = 0; j < 4; ++j) {
            int row = g * 4 + j;
            z1t[row * ZP + col] = f2b(fmaxf(acc1[t][j] + bv, 0.f));
        }
    }
    __syncthreads();

    // ---- phase 3: m2 ----
    bf16x8 a2[4];
#pragma unroll
    for (int ks = 0; ks < 4; ++ks)
        a2[ks] = *reinterpret_cast<const bf16x8*>(z1t + c * ZP + ks * 32 + g * 8);

    f32x4 acc2[2];
    acc2[0] = (f32x4){0.f, 0.f, 0.f, 0.f};
    acc2[1] = (f32x4){0.f, 0.f, 0.f, 0.f};
#pragma unroll
    for (int t = 0; t < 2; ++t) {
        int ct = wid * 2 + t;
#pragma unroll
        for (int ks = 0; ks < 4; ++ks) {
            bf16x8 b = *reinterpret_cast<const bf16x8*>(
                wf2 + (((ct * 4 + ks) * 64 + lane) << 3));
            acc2[t] = __builtin_amdgcn_mfma_f32_16x16x32_bf16(a2[ks], b, acc2[t], 0, 0, 0);
        }
    }

    // ep2: bn + relu -> hout (skipped on last layer), pooled
    int ga = gidx[r0], gb = gidx[r0 + 15];
    bool uni = (ga == gb);
#pragma unroll
    for (int t = 0; t < 2; ++t) {
        int col = (wid * 2 + t) * 16 + c;
        float scl = sclp[col], sh = shp[col];
        float hv[4];
        float psum = 0.f;
#pragma unroll
        for (int j = 0; j < 4; ++j) {
            int row = g * 4 + j;
            float v = fmaxf(fmaf(acc2[t][j], scl, sh), 0.f);
            hv[j] = v;
            psum += v;
            if (STORE_H) hout[(size_t)(r0 + row) * U + col] = f2b(v);
        }
        if (uni) {
            psum += __shfl_xor(psum, 16);
            psum += __shfl_xor(psum, 32);
            if (lane < 16)
                unsafeAtomicAdd(&pooled[(size_t)ga * (NGIN * U) + pool_off + col], psum);
        } else {
#pragma unroll
            for (int j = 0; j < 4; ++j)
                unsafeAtomicAdd(&pooled[(size_t)gidx[r0 + g * 4 + j] * (NGIN * U) + pool_off + col], hv[j]);
        }
    }
}

// ---------------------------------------------------------------------------
// merged readout MLP: g = relu(pooled@Wm1+bm1); logits = g@Wm2+bm2
// ---------------------------------------------------------------------------
__global__ __launch_bounds__(128) void mlp_k(const float* __restrict__ pooled,
                                             const float* __restrict__ Wm1,
                                             const float* __restrict__ bm1,
                                             const float* __restrict__ Wm2,
                                             const float* __restrict__ bm2,
                                             float* __restrict__ out) {
    __shared__ float sp[NGIN * U];
    __shared__ float sg[128];
    int gi = blockIdx.x, c = threadIdx.x;
    for (int j = c; j < NGIN * U; j += 128) sp[j] = pooled[(size_t)gi * (NGIN * U) + j];
    __syncthreads();
    float acc = bm1[c];
    for (int k = 0; k < NGIN * U; ++k) acc = fmaf(sp[k], Wm1[(size_t)k * 128 + c], acc);
    sg[c] = fmaxf(acc, 0.f);
    __syncthreads();
    if (c < 16) {
        float a2 = bm2[c];
        for (int k = 0; k < 128; ++k) a2 = fmaf(sg[k], Wm2[k * 16 + c], a2);
        out[gi * 16 + c] = a2;
    }
}

extern "C" void kernel_launch(void* const* d_in, const int* in_sizes, int n_in,
                              void* d_out, int out_size, void* d_ws, size_t ws_size,
                              hipStream_t stream) {
    const float* x   = (const float*)d_in[0];
    const int*   ei  = (const int*)d_in[1];
    const float* ew  = (const float*)d_in[2];
    const int*   gix = (const int*)d_in[3];
    const float* W1  = (const float*)d_in[4];
    const float* b1  = (const float*)d_in[5];
    const float* W2  = (const float*)d_in[6];
    const float* b2  = (const float*)d_in[7];
    const float* gam = (const float*)d_in[8];
    const float* bet = (const float*)d_in[9];
    const float* bmn = (const float*)d_in[10];
    const float* bvr = (const float*)d_in[11];
    const float* Wm1 = (const float*)d_in[12];
    const float* bm1 = (const float*)d_in[13];
    const float* Wm2 = (const float*)d_in[14];
    const float* bm2 = (const float*)d_in[15];
    float* out = (float*)d_out;

    unsigned short* hb0 = (unsigned short*)d_ws;
    unsigned short* hb1 = hb0 + (size_t)NN * U;
    float* pooled = (float*)(hb1 + (size_t)NN * U);
    unsigned short* wfrag = (unsigned short*)(pooled + (size_t)NG * (NGIN * U));
    unsigned* esw = (unsigned*)(wfrag + 6 * 16384);
    uint2* tmp    = (uint2*)(esw + (size_t)NBUCK * BCAP);
    int*   rowptr = (int*)(tmp + (size_t)NBUCK * BCAP);
    int*   rowend = rowptr + NN;
    int*   bcur   = rowend + NN;
    float* sclp   = (float*)(bcur + NBUCK);
    float* shp    = sclp + NGIN * U;

    // one merged prep launch
    prep_k<<<CVTB + 6 + 3 + 24 + 1, 256, 0, stream>>>(
        x, hb0, W1, W2, wfrag, b2, gam, bet, bmn, bvr, sclp, shp, pooled, bcur);
    phaseA_k<<<NAB, 256, 0, stream>>>(ei, ew, bcur, tmp);
    phaseB_k<<<NBUCK, 256, 0, stream>>>(tmp, bcur, rowptr, rowend, esw);

    // layer 1: x->h1 ; layer 2: h1->h2 ; layer 3: h2 -> pooled only
    fusedgd_k<true><<<NN / 16, 256, 0, stream>>>(
        hb0, esw, rowptr, rowend,
        wfrag, wfrag + 16384,
        b1, sclp, shp, gix, hb1, pooled, 0);
    fusedgd_k<true><<<NN / 16, 256, 0, stream>>>(
        hb1, esw, rowptr, rowend,
        wfrag + 2 * 16384, wfrag + 3 * 16384,
        b1 + U, sclp + U, shp + U, gix, hb0, pooled, U);
    fusedgd_k<false><<<NN / 16, 256, 0, stream>>>(
        hb0, esw, rowptr, rowend,
        wfrag + 4 * 16384, wfrag + 5 * 16384,
        b1 + 2 * U, sclp + 2 * U, shp + 2 * U, gix, hb1, pooled, 2 * U);

    mlp_k<<<NG, 128, 0, stream>>>(pooled, Wm1, bm1, Wm2, bm2, out);
}